// Round 6
// baseline (23369.391 us; speedup 1.0000x reference)
//
#include <hip/hip_runtime.h>
#include <hip/hip_bf16.h>
#include <cstdint>
#include <cstdio>

// Problem constants
#define B_   64
#define U_   512
#define D_   512
#define H_   640
#define P_   512
#define G4H  2560   // 4*H
#define NWG  40     // WGs in persistent recurrent kernel

typedef __bf16 bf16x8 __attribute__((ext_vector_type(8)));
typedef float  f32x4  __attribute__((ext_vector_type(4)));

__device__ __forceinline__ float sigm(float x)     { return 1.f / (1.f + __expf(-x)); }
__device__ __forceinline__ float tanhfast(float x) { return 1.f - 2.f / (1.f + __expf(2.f * x)); }

// IC-direct (bypass L1 + per-XCD L2) flag ops — explicit sc0 sc1, no reliance
// on LLVM's scope lowering.
__device__ __forceinline__ void sysflag_store(unsigned* p, unsigned v) {
    asm volatile("global_store_dword %0, %1, off sc0 sc1" :: "v"(p), "v"(v) : "memory");
}
__device__ __forceinline__ unsigned sysflag_load(const unsigned* p) {
    unsigned r;
    asm volatile("global_load_dword %0, %1, off sc0 sc1\n\ts_waitcnt vmcnt(0)"
                 : "=v"(r) : "v"(p) : "memory");
    return r;
}

// ---------------------------------------------------------------------------
// Weight convert + transpose: W[K][N] f32 -> WT[N'][K] bf16.
// reorder=1 remaps gate-major columns (n = g*640+j) to interleaved (n' = 4j+g).
__global__ __launch_bounds__(256) void wconv_kernel(
    const float* __restrict__ W, __bf16* __restrict__ WT, int K, int N, int reorder) {
    int tid = blockIdx.x * 256 + threadIdx.x;
    if (tid >= K * N) return;
    int k = tid / N, n = tid % N;
    int np = reorder ? (4 * (n % 640) + (n / 640)) : n;
    WT[(size_t)np * K + k] = (__bf16)W[(size_t)k * N + n];
}

__global__ __launch_bounds__(256) void breorder_kernel(
    const float* __restrict__ b, float* __restrict__ br) {
    int n = blockIdx.x * 256 + threadIdx.x;
    if (n < G4H) br[4 * (n % 640) + (n / 640)] = b[n];
}

// Embedding gather -> bf16, 4 elems/thread
__global__ __launch_bounds__(256) void gather_kernel(
    const int* __restrict__ tokens, const float* __restrict__ embed,
    __bf16* __restrict__ X) {
    int tid = blockIdx.x * 256 + threadIdx.x;
    int row = tid >> 7;
    int c4  = (tid & 127) << 2;
    int tok = tokens[row];
    float4 v = *reinterpret_cast<const float4*>(embed + (size_t)tok * D_ + c4);
    union { ushort4 u; __bf16 h[4]; } o;
    o.h[0] = (__bf16)v.x; o.h[1] = (__bf16)v.y; o.h[2] = (__bf16)v.z; o.h[3] = (__bf16)v.w;
    *reinterpret_cast<ushort4*>(X + (size_t)row * D_ + c4) = o.u;
}

// Zero h ping-pong buffers + barrier flags
__global__ __launch_bounds__(256) void zstate_kernel(
    __bf16* __restrict__ h0, __bf16* __restrict__ h1, unsigned* __restrict__ bar) {
    int tid = blockIdx.x * 256 + threadIdx.x;
    if (tid < B_ * H_) { h0[tid] = (__bf16)0.f; h1[tid] = (__bf16)0.f; }
    if (tid < 128) bar[tid] = 0u;
}

// ---------------------------------------------------------------------------
// Generic bf16 MFMA GEMM: C[M][N] = A[M][K] @ BT[N][K]^T + bias[N]
// ztr=1 writes rows transposed (row = b*U+u  ->  out row u*B+b), for Z.
__global__ __launch_bounds__(256) void gemm_kernel(
    const __bf16* __restrict__ A, const __bf16* __restrict__ BT,
    const float* __restrict__ bias,
    float* __restrict__ Cf, __bf16* __restrict__ Cb,
    int M, int N, int K, int ztr) {
    const int wv = threadIdx.x >> 6, l = threadIdx.x & 63;
    const int lr = l & 15, lh = l >> 4;
    const int m0 = blockIdx.y * 64 + wv * 16;
    const int n0 = blockIdx.x * 64;

    f32x4 acc[4];
    #pragma unroll
    for (int nt = 0; nt < 4; ++nt) acc[nt] = (f32x4){0.f, 0.f, 0.f, 0.f};

    const __bf16* Ap = A  + (size_t)(m0 + lr) * K + lh * 8;
    const __bf16* Bp = BT + (size_t)(n0 + lr) * K + lh * 8;
    for (int k0 = 0; k0 < K; k0 += 32) {
        bf16x8 af = *reinterpret_cast<const bf16x8*>(Ap + k0);
        #pragma unroll
        for (int nt = 0; nt < 4; ++nt) {
            bf16x8 bfv = *reinterpret_cast<const bf16x8*>(Bp + (size_t)nt * 16 * K + k0);
            acc[nt] = __builtin_amdgcn_mfma_f32_16x16x32_bf16(af, bfv, acc[nt], 0, 0, 0);
        }
    }
    #pragma unroll
    for (int nt = 0; nt < 4; ++nt) {
        int col = n0 + nt * 16 + lr;
        float bs = bias ? bias[col] : 0.f;
        #pragma unroll
        for (int r = 0; r < 4; ++r) {
            int row = m0 + lh * 4 + r;
            int crow = ztr ? ((row & (U_ - 1)) * B_ + (row >> 9)) : row;
            float v = acc[nt][r] + bs;
            if (Cf) Cf[(size_t)crow * N + col] = v;
            else    Cb[(size_t)crow * N + col] = (__bf16)v;
        }
    }
}

// ---------------------------------------------------------------------------
// Persistent LSTM sequence kernel. Grid: NWG=40 WGs x 256 (cooperative launch
// for co-residency). Custom grid barrier per step with EXPLICIT cache control:
//   release: per-thread vmcnt(0) -> syncthreads -> tid0 buffer_wbl2 (flush XCD
//            L2 -> IC) + wait -> arrival flag (IC-direct store)
//   gather:  WG0 wave0 polls all 40 flags (IC-direct loads), publishes go-flag
//   acquire: spin go-flag (IC-direct) -> syncthreads -> buffer_inv (invalidate
//            L1 + XCD L2) so normal cached h loads refetch from IC.
// WG w owns reordered gate cols [64w,64w+64) == j in [16w,16w+16).
// Wh B-fragments register-resident (20 x bf16x8); c,h state in registers.
__global__ __launch_bounds__(256, 1) void lstm_seq_kernel(
    const __bf16* __restrict__ Z,       // [U][B][G4H] bf16 (pre-transposed)
    const __bf16* __restrict__ WhT,     // [G4H][H_] reordered rows
    __bf16* h0,                         // [B_][H_] ping
    __bf16* h1,                         // [B_][H_] pong
    __bf16* __restrict__ Hout,          // [B_][U_][H_]
    const int* __restrict__ plen,
    unsigned* bar) {                    // bar[0..39]=arrival, bar[64]=go
    __shared__ float zl[64 * 65];
    const int w = blockIdx.x, tid = threadIdx.x;
    const int wv = tid >> 6, l = tid & 63;
    const int lr = l & 15, lh = l >> 4;

    // Wh slice -> registers (one-time). 20 k-tiles of bf16x8 per lane.
    bf16x8 wreg[20];
    {
        const __bf16* Bp = WhT + (size_t)(w * 64 + wv * 16 + lr) * H_ + lh * 8;
        #pragma unroll
        for (int kk = 0; kk < 20; ++kk)
            wreg[kk] = *reinterpret_cast<const bf16x8*>(Bp + kk * 32);
    }

    // Gate-phase constants: thread owns (bb0,jp),(bb1,jp), 2 adjacent cols each
    const int bb0 = tid >> 3, jp = tid & 7;
    const int bb1 = bb0 + 32;
    const int pl0 = plen[bb0], pl1 = plen[bb1];
    float c_r[4] = {0.f, 0.f, 0.f, 0.f};
    float h_r[4] = {0.f, 0.f, 0.f, 0.f};

    for (unsigned t = 0; t < U_; ++t) {
        const __bf16* hin  = (t & 1u) ? h1 : h0;
        __bf16*       hout = (t & 1u) ? h0 : h1;

        // Issue this step's Z reads early (HBM latency hides under MFMAs)
        bf16x8 zq0 = *reinterpret_cast<const bf16x8*>(
            Z + ((size_t)t * B_ + bb0) * G4H + w * 64 + 8 * jp);
        bf16x8 zq1 = *reinterpret_cast<const bf16x8*>(
            Z + ((size_t)t * B_ + bb1) * G4H + w * 64 + 8 * jp);

        // h @ Wh : A from global hin (normal cached loads), B from registers
        f32x4 acc[4];
        #pragma unroll
        for (int mt = 0; mt < 4; ++mt) acc[mt] = (f32x4){0.f, 0.f, 0.f, 0.f};
        const __bf16* Apb = hin + (size_t)lr * H_ + lh * 8;
        #pragma unroll
        for (int kk = 0; kk < 20; ++kk) {
            #pragma unroll
            for (int mt = 0; mt < 4; ++mt) {
                bf16x8 af = *reinterpret_cast<const bf16x8*>(
                    Apb + (size_t)mt * 16 * H_ + kk * 32);
                acc[mt] = __builtin_amdgcn_mfma_f32_16x16x32_bf16(af, wreg[kk], acc[mt], 0, 0, 0);
            }
        }
        // redistribute h@Wh through LDS (MFMA layout -> gate layout)
        {
            int cl = wv * 16 + lr;
            #pragma unroll
            for (int mt = 0; mt < 4; ++mt)
                #pragma unroll
                for (int r = 0; r < 4; ++r)
                    zl[(mt * 16 + lh * 4 + r) * 65 + cl] = acc[mt][r];
        }
        __syncthreads();

        // gates + masked state update (registers); h broadcast via normal stores
        #pragma unroll
        for (int it = 0; it < 2; ++it) {
            const int bb = it ? bb1 : bb0;
            const int pl = it ? pl1 : pl0;
            const bf16x8 zq = it ? zq1 : zq0;
            const float* zp = &zl[bb * 65 + 8 * jp];
            union { __bf16 h[2]; unsigned u; } pk;
            #pragma unroll
            for (int e = 0; e < 2; ++e) {
                const int s = it * 2 + e;
                float zi = zp[4 * e + 0] + (float)zq[4 * e + 0];
                float zf = zp[4 * e + 1] + (float)zq[4 * e + 1];
                float zg = zp[4 * e + 2] + (float)zq[4 * e + 2];
                float zo = zp[4 * e + 3] + (float)zq[4 * e + 3];
                float ig = sigm(zi), fg = sigm(zf), og = sigm(zo);
                float gg = tanhfast(zg);
                float cnew = fg * c_r[s] + ig * gg;
                float hnew = og * tanhfast(cnew);
                bool m = (int)t < pl;
                c_r[s] = m ? cnew : c_r[s];
                h_r[s] = m ? hnew : h_r[s];
                pk.h[e] = (__bf16)h_r[s];
            }
            const size_t co = (size_t)w * 16 + 2 * jp;
            *reinterpret_cast<unsigned*>(hout + (size_t)bb * H_ + co) = pk.u;
            *reinterpret_cast<unsigned*>(Hout + ((size_t)bb * U_ + t) * H_ + co) = pk.u;
        }

        // ---- custom grid barrier with explicit cache control ----
        const unsigned gen = t + 1u;
        asm volatile("s_waitcnt vmcnt(0)" ::: "memory");   // own stores at L2
        __syncthreads();
        if (tid == 0) {
            // flush this XCD's L2 to the IC, then publish arrival
            asm volatile("buffer_wbl2 sc1\n\ts_waitcnt vmcnt(0)" ::: "memory");
            sysflag_store(&bar[w], gen);
        }
        if (w == 0) {
            if (wv == 0) {
                bool ok;
                do {
                    unsigned f = sysflag_load(&bar[l]);
                    ok = (l < NWG) ? (f >= gen) : true;
                } while (__ballot(ok) != ~0ull);
                if (l == 0) sysflag_store(&bar[64], gen);
            }
        } else if (tid == 0) {
            while (sysflag_load(&bar[64]) < gen) {}
        }
        __syncthreads();
        // invalidate stale L1/XCD-L2 lines; next h loads refetch from IC
        asm volatile("buffer_inv sc1" ::: "memory");
        __builtin_amdgcn_sched_barrier(0);
    }
}

// ---------------------------------------------------------------------------
// In-place LayerNorm over H_=640 per row (bf16 in/out, f32 stats)
__global__ __launch_bounds__(256) void ln_kernel(
    __bf16* __restrict__ X, const float* __restrict__ gamma, const float* __restrict__ beta) {
    __shared__ float s1[256];
    __shared__ float s2[256];
    const int tid = threadIdx.x;
    __bf16* xp = X + (size_t)blockIdx.x * H_;
    float xv[3] = {0.f, 0.f, 0.f};
    float a = 0.f, b = 0.f;
    #pragma unroll
    for (int i = 0; i < 3; ++i) {
        int j = tid + 256 * i;
        if (j < H_) { float v = (float)xp[j]; xv[i] = v; a += v; b += v * v; }
    }
    s1[tid] = a; s2[tid] = b;
    __syncthreads();
    for (int st = 128; st > 0; st >>= 1) {
        if (tid < st) { s1[tid] += s1[tid + st]; s2[tid] += s2[tid + st]; }
        __syncthreads();
    }
    float mean = s1[0] * (1.f / H_);
    float var  = s2[0] * (1.f / H_) - mean * mean;
    float inv  = rsqrtf(var + 0.001f);
    #pragma unroll
    for (int i = 0; i < 3; ++i) {
        int j = tid + 256 * i;
        if (j < H_) xp[j] = (__bf16)((xv[i] - mean) * inv * gamma[j] + beta[j]);
    }
}

// ---------------------------------------------------------------------------
extern "C" void kernel_launch(void* const* d_in, const int* in_sizes, int n_in,
                              void* d_out, int out_size, void* d_ws, size_t ws_size,
                              hipStream_t stream) {
    (void)in_sizes; (void)n_in; (void)out_size;
    const int*   tokens = (const int*)d_in[0];
    const int*   plen   = (const int*)d_in[1];
    const float* embed  = (const float*)d_in[2];
    const float* W0x = (const float*)d_in[3];
    const float* W0h = (const float*)d_in[4];
    const float* b0  = (const float*)d_in[5];
    const float* g0  = (const float*)d_in[6];
    const float* be0 = (const float*)d_in[7];
    const float* P0w = (const float*)d_in[8];
    const float* P0b = (const float*)d_in[9];
    const float* W1x = (const float*)d_in[10];
    const float* W1h = (const float*)d_in[11];
    const float* b1  = (const float*)d_in[12];
    const float* g1  = (const float*)d_in[13];
    const float* be1 = (const float*)d_in[14];
    const float* P1w = (const float*)d_in[15];
    const float* P1b = (const float*)d_in[16];
    float* out = (float*)d_out;

    char* p = (char*)d_ws;
    size_t used = 0;
    auto take = [&](size_t bytes) {
        char* r = p; size_t pad = (bytes + 255) & ~(size_t)255;
        p += pad; used += pad; return r;
    };
    __bf16* WT0x_ = (__bf16*)take((size_t)G4H * D_ * 2);
    __bf16* WT0h_ = (__bf16*)take((size_t)G4H * H_ * 2);
    __bf16* WT1x_ = (__bf16*)take((size_t)G4H * P_ * 2);
    __bf16* WT1h_ = (__bf16*)take((size_t)G4H * H_ * 2);
    __bf16* PT0w_ = (__bf16*)take((size_t)P_ * H_ * 2);
    __bf16* PT1w_ = (__bf16*)take((size_t)P_ * H_ * 2);
    float*  b0r   = (float*)take(G4H * 4);
    float*  b1r   = (float*)take(G4H * 4);
    __bf16* hb0   = (__bf16*)take((size_t)B_ * H_ * 2);
    __bf16* hb1   = (__bf16*)take((size_t)B_ * H_ * 2);
    unsigned* bar = (unsigned*)take(512);
    __bf16* Hbuf  = (__bf16*)take((size_t)B_ * U_ * H_ * 2);   // h outputs, LN'd in place
    __bf16* Z     = (__bf16*)take((size_t)B_ * U_ * G4H * 2);  // pre-activations [U][B][4H]

    if (used > ws_size) {
        fprintf(stderr, "kernel_launch: ws_size too small (%zu < %zu)\n",
                ws_size, used);
        return;
    }
    // Xbf aliases d_out (67 MB f32): dead before the final GEMM overwrites d_out.
    __bf16* Xbf = (__bf16*)d_out;

    dim3 blk(256);
    wconv_kernel<<<(D_ * G4H + 255) / 256, blk, 0, stream>>>(W0x, WT0x_, D_, G4H, 1);
    wconv_kernel<<<(H_ * G4H + 255) / 256, blk, 0, stream>>>(W0h, WT0h_, H_, G4H, 1);
    wconv_kernel<<<(P_ * G4H + 255) / 256, blk, 0, stream>>>(W1x, WT1x_, P_, G4H, 1);
    wconv_kernel<<<(H_ * G4H + 255) / 256, blk, 0, stream>>>(W1h, WT1h_, H_, G4H, 1);
    wconv_kernel<<<(H_ * P_ + 255) / 256, blk, 0, stream>>>(P0w, PT0w_, H_, P_, 0);
    wconv_kernel<<<(H_ * P_ + 255) / 256, blk, 0, stream>>>(P1w, PT1w_, H_, P_, 0);
    breorder_kernel<<<10, blk, 0, stream>>>(b0, b0r);
    breorder_kernel<<<10, blk, 0, stream>>>(b1, b1r);
    gather_kernel<<<(B_ * U_ * D_ / 4 + 255) / 256, blk, 0, stream>>>(tokens, embed, Xbf);

    // ---- layer 0 ----
    gemm_kernel<<<dim3(G4H / 64, B_ * U_ / 64), blk, 0, stream>>>(
        Xbf, WT0x_, b0r, nullptr, Z, B_ * U_, G4H, D_, 1);
    zstate_kernel<<<(B_ * H_ + 255) / 256, blk, 0, stream>>>(hb0, hb1, bar);
    {
        const __bf16* Zc = Z; const __bf16* Wc = WT0h_;
        __bf16* h0a = hb0; __bf16* h1a = hb1; __bf16* Ha = Hbuf;
        const int* pl = plen; unsigned* ba = bar;
        void* args[] = { (void*)&Zc, (void*)&Wc, (void*)&h0a, (void*)&h1a,
                         (void*)&Ha, (void*)&pl, (void*)&ba };
        (void)hipLaunchCooperativeKernel((void*)lstm_seq_kernel, dim3(NWG), dim3(256),
                                         args, 0, stream);
    }
    ln_kernel<<<B_ * U_, blk, 0, stream>>>(Hbuf, g0, be0);
    gemm_kernel<<<dim3(P_ / 64, B_ * U_ / 64), blk, 0, stream>>>(
        Hbuf, PT0w_, P0b, nullptr, Xbf, B_ * U_, P_, H_, 0);

    // ---- layer 1 ----
    gemm_kernel<<<dim3(G4H / 64, B_ * U_ / 64), blk, 0, stream>>>(
        Xbf, WT1x_, b1r, nullptr, Z, B_ * U_, G4H, P_, 1);
    zstate_kernel<<<(B_ * H_ + 255) / 256, blk, 0, stream>>>(hb0, hb1, bar);
    {
        const __bf16* Zc = Z; const __bf16* Wc = WT1h_;
        __bf16* h0a = hb0; __bf16* h1a = hb1; __bf16* Ha = Hbuf;
        const int* pl = plen; unsigned* ba = bar;
        void* args[] = { (void*)&Zc, (void*)&Wc, (void*)&h0a, (void*)&h1a,
                         (void*)&Ha, (void*)&pl, (void*)&ba };
        (void)hipLaunchCooperativeKernel((void*)lstm_seq_kernel, dim3(NWG), dim3(256),
                                         args, 0, stream);
    }
    ln_kernel<<<B_ * U_, blk, 0, stream>>>(Hbuf, g1, be1);
    gemm_kernel<<<dim3(P_ / 64, B_ * U_ / 64), blk, 0, stream>>>(
        Hbuf, PT1w_, P1b, out, nullptr, B_ * U_, P_, H_, 0);
}

// Round 9
// 14628.586 us; speedup vs baseline: 1.5975x; 1.5975x over previous
//
#include <hip/hip_runtime.h>
#include <hip/hip_bf16.h>
#include <cstdint>
#include <cstdio>

// Problem constants
#define B_   64
#define U_   512
#define D_   512
#define H_   640
#define P_   512
#define G4H  2560   // 4*H
#define NWG  40     // WGs in recurrent kernels

typedef __bf16 bf16x8 __attribute__((ext_vector_type(8)));
typedef float  f32x4  __attribute__((ext_vector_type(4)));
typedef int    i32x4  __attribute__((ext_vector_type(4)));

__device__ __forceinline__ float sigm(float x)     { return 1.f / (1.f + __expf(-x)); }
__device__ __forceinline__ float tanhfast(float x) { return 1.f - 2.f / (1.f + __expf(2.f * x)); }

// IC-direct (bypass L1 + per-XCD L2) ops — explicit sc0 sc1.
__device__ __forceinline__ void sysflag_store(unsigned* p, unsigned v) {
    asm volatile("global_store_dword %0, %1, off sc0 sc1" :: "v"(p), "v"(v) : "memory");
}
__device__ __forceinline__ unsigned sysflag_load(const unsigned* p) {
    unsigned r;
    asm volatile("global_load_dword %0, %1, off sc0 sc1\n\ts_waitcnt vmcnt(0)"
                 : "=v"(r) : "v"(p) : "memory");
    return r;
}
// Uncached 16B load (issue only — caller must s_waitcnt vmcnt(0) before use)
__device__ __forceinline__ i32x4 icload_b128(const void* p) {
    i32x4 r;
    asm volatile("global_load_dwordx4 %0, %1, off sc0 sc1"
                 : "=v"(r) : "v"(p) : "memory");
    return r;
}

// ---------------------------------------------------------------------------
__global__ __launch_bounds__(256) void wconv_kernel(
    const float* __restrict__ W, __bf16* __restrict__ WT, int K, int N, int reorder) {
    int tid = blockIdx.x * 256 + threadIdx.x;
    if (tid >= K * N) return;
    int k = tid / N, n = tid % N;
    int np = reorder ? (4 * (n % 640) + (n / 640)) : n;
    WT[(size_t)np * K + k] = (__bf16)W[(size_t)k * N + n];
}

__global__ __launch_bounds__(256) void breorder_kernel(
    const float* __restrict__ b, float* __restrict__ br) {
    int n = blockIdx.x * 256 + threadIdx.x;
    if (n < G4H) br[4 * (n % 640) + (n / 640)] = b[n];
}

__global__ __launch_bounds__(256) void gather_kernel(
    const int* __restrict__ tokens, const float* __restrict__ embed,
    __bf16* __restrict__ X) {
    int tid = blockIdx.x * 256 + threadIdx.x;
    int row = tid >> 7;
    int c4  = (tid & 127) << 2;
    int tok = tokens[row];
    float4 v = *reinterpret_cast<const float4*>(embed + (size_t)tok * D_ + c4);
    union { ushort4 u; __bf16 h[4]; } o;
    o.h[0] = (__bf16)v.x; o.h[1] = (__bf16)v.y; o.h[2] = (__bf16)v.z; o.h[3] = (__bf16)v.w;
    *reinterpret_cast<ushort4*>(X + (size_t)row * D_ + c4) = o.u;
}

// Zero h ping-pong buffers + global c state + barrier flags
__global__ __launch_bounds__(256) void zstate_kernel(
    __bf16* __restrict__ h0, __bf16* __restrict__ h1,
    float* __restrict__ cst, unsigned* __restrict__ bar) {
    int tid = blockIdx.x * 256 + threadIdx.x;
    if (tid < B_ * H_) { h0[tid] = (__bf16)0.f; h1[tid] = (__bf16)0.f; cst[tid] = 0.f; }
    if (tid < 128) bar[tid] = 0u;
}

// ---------------------------------------------------------------------------
// Generic bf16 MFMA GEMM: C[M][N] = A[M][K] @ BT[N][K]^T + bias[N]
// ztr=1 writes rows transposed (row = b*U+u -> out row u*B+b), for Z.
__global__ __launch_bounds__(256) void gemm_kernel(
    const __bf16* __restrict__ A, const __bf16* __restrict__ BT,
    const float* __restrict__ bias,
    float* __restrict__ Cf, __bf16* __restrict__ Cb,
    int M, int N, int K, int ztr) {
    const int wv = threadIdx.x >> 6, l = threadIdx.x & 63;
    const int lr = l & 15, lh = l >> 4;
    const int m0 = blockIdx.y * 64 + wv * 16;
    const int n0 = blockIdx.x * 64;

    f32x4 acc[4];
    #pragma unroll
    for (int nt = 0; nt < 4; ++nt) acc[nt] = (f32x4){0.f, 0.f, 0.f, 0.f};

    const __bf16* Ap = A  + (size_t)(m0 + lr) * K + lh * 8;
    const __bf16* Bp = BT + (size_t)(n0 + lr) * K + lh * 8;
    for (int k0 = 0; k0 < K; k0 += 32) {
        bf16x8 af = *reinterpret_cast<const bf16x8*>(Ap + k0);
        #pragma unroll
        for (int nt = 0; nt < 4; ++nt) {
            bf16x8 bfv = *reinterpret_cast<const bf16x8*>(Bp + (size_t)nt * 16 * K + k0);
            acc[nt] = __builtin_amdgcn_mfma_f32_16x16x32_bf16(af, bfv, acc[nt], 0, 0, 0);
        }
    }
    #pragma unroll
    for (int nt = 0; nt < 4; ++nt) {
        int col = n0 + nt * 16 + lr;
        float bs = bias ? bias[col] : 0.f;
        #pragma unroll
        for (int r = 0; r < 4; ++r) {
            int row = m0 + lh * 4 + r;
            int crow = ztr ? ((row & (U_ - 1)) * B_ + (row >> 9)) : row;
            float v = acc[nt][r] + bs;
            if (Cf) Cf[(size_t)crow * N + col] = v;
            else    Cb[(size_t)crow * N + col] = (__bf16)v;
        }
    }
}

// ---------------------------------------------------------------------------
// Persistent LSTM kernel (cooperative). R6-proven resource shape: static LDS
// 16,640 B only, smem arg 0. h exchange is IC-direct (sc0 sc1) both sides ->
// flags-only grid barrier (no wbl2/buffer_inv). MFMA A-frags load straight
// from IC (per-mt batches of 20 in-flight dwordx4).
__global__ __launch_bounds__(256, 1) void lstm_seq_kernel(
    const __bf16* __restrict__ Z,       // [U][B][G4H] bf16 (pre-transposed)
    const __bf16* __restrict__ WhT,     // [G4H][H_] reordered rows
    __bf16* h0, __bf16* h1,             // [B_][H_] ping-pong
    __bf16* __restrict__ Hout,          // [B_][U_][H_]
    const int* __restrict__ plen,
    unsigned* bar) {                    // bar[0..39]=arrival, bar[64]=go
    __shared__ float zl[64 * 65];       // 16,640 B (static, under 64 KB)
    const int w = blockIdx.x, tid = threadIdx.x;
    const int wv = tid >> 6, l = tid & 63;
    const int lr = l & 15, lh = l >> 4;

    // Wh slice -> registers (one-time, cached loads). 20 k-tiles of bf16x8.
    bf16x8 wreg[20];
    {
        const __bf16* Bp = WhT + (size_t)(w * 64 + wv * 16 + lr) * H_ + lh * 8;
        #pragma unroll
        for (int kk = 0; kk < 20; ++kk)
            wreg[kk] = *reinterpret_cast<const bf16x8*>(Bp + kk * 32);
    }

    const int bb0 = tid >> 3, jp = tid & 7;
    const int bb1 = bb0 + 32;
    const int pl0 = plen[bb0], pl1 = plen[bb1];
    float c_r[4] = {0.f, 0.f, 0.f, 0.f};
    float h_r[4] = {0.f, 0.f, 0.f, 0.f};

    for (unsigned t = 0; t < U_; ++t) {
        const __bf16* hin  = (t & 1u) ? h1 : h0;
        __bf16*       hout = (t & 1u) ? h0 : h1;

        // Z reads (cached; issued first, latency hides under h phase)
        bf16x8 zq0 = *reinterpret_cast<const bf16x8*>(
            Z + ((size_t)t * B_ + bb0) * G4H + w * 64 + 8 * jp);
        bf16x8 zq1 = *reinterpret_cast<const bf16x8*>(
            Z + ((size_t)t * B_ + bb1) * G4H + w * 64 + 8 * jp);

        // h @ Wh : A-frags via IC-direct loads, B from registers
        f32x4 acc[4];
        #pragma unroll
        for (int mt = 0; mt < 4; ++mt) acc[mt] = (f32x4){0.f, 0.f, 0.f, 0.f};
        const __bf16* Ab = hin + (size_t)lr * H_ + lh * 8;
        #pragma unroll
        for (int mt = 0; mt < 4; ++mt) {
            i32x4 hr[20];
            #pragma unroll
            for (int kk = 0; kk < 20; ++kk)
                hr[kk] = icload_b128(Ab + (size_t)mt * 16 * H_ + kk * 32);
            asm volatile("s_waitcnt vmcnt(0)" ::: "memory");
            __builtin_amdgcn_sched_barrier(0);
            #pragma unroll
            for (int kk = 0; kk < 20; ++kk) {
                union { i32x4 i; bf16x8 h; } cv; cv.i = hr[kk];
                acc[mt] = __builtin_amdgcn_mfma_f32_16x16x32_bf16(cv.h, wreg[kk], acc[mt], 0, 0, 0);
            }
        }
        // redistribute h@Wh through LDS (MFMA layout -> gate layout)
        {
            int cl = wv * 16 + lr;
            #pragma unroll
            for (int mt = 0; mt < 4; ++mt)
                #pragma unroll
                for (int r = 0; r < 4; ++r)
                    zl[(mt * 16 + lh * 4 + r) * 65 + cl] = acc[mt][r];
        }
        __syncthreads();

        // gates + masked state update; h broadcast via IC-direct stores
        #pragma unroll
        for (int it = 0; it < 2; ++it) {
            const int bb = it ? bb1 : bb0;
            const int pl = it ? pl1 : pl0;
            const bf16x8 zq = it ? zq1 : zq0;
            const float* zp = &zl[bb * 65 + 8 * jp];
            union { __bf16 h[2]; unsigned u; } pk;
            #pragma unroll
            for (int e = 0; e < 2; ++e) {
                const int s = it * 2 + e;
                float zi = zp[4 * e + 0] + (float)zq[4 * e + 0];
                float zf = zp[4 * e + 1] + (float)zq[4 * e + 1];
                float zg = zp[4 * e + 2] + (float)zq[4 * e + 2];
                float zo = zp[4 * e + 3] + (float)zq[4 * e + 3];
                float ig = sigm(zi), fg = sigm(zf), og = sigm(zo);
                float gg = tanhfast(zg);
                float cnew = fg * c_r[s] + ig * gg;
                float hnew = og * tanhfast(cnew);
                bool m = (int)t < pl;
                c_r[s] = m ? cnew : c_r[s];
                h_r[s] = m ? hnew : h_r[s];
                pk.h[e] = (__bf16)h_r[s];
            }
            const size_t co = (size_t)w * 16 + 2 * jp;
            sysflag_store((unsigned*)(hout + (size_t)bb * H_ + co), pk.u);
            *reinterpret_cast<unsigned*>(Hout + ((size_t)bb * U_ + t) * H_ + co) = pk.u;
        }

        // grid barrier: flags only (h at IC once vmcnt drains)
        const unsigned gen = t + 1u;
        asm volatile("s_waitcnt vmcnt(0)" ::: "memory");
        __syncthreads();
        if (tid == 0) sysflag_store(&bar[w], gen);
        if (w == 0) {
            if (wv == 0) {
                bool ok;
                do {
                    unsigned f = sysflag_load(&bar[l]);
                    ok = (l < NWG) ? (f >= gen) : true;
                } while (__ballot(ok) != ~0ull);
                if (l == 0) sysflag_store(&bar[64], gen);
            }
        } else if (tid == 0) {
            while (sysflag_load(&bar[64]) < gen) {}
        }
        __syncthreads();
    }
}

// ---------------------------------------------------------------------------
// Fallback: one launch per timestep (no grid barrier, inter-dispatch coherence).
// Same math; c state in global, h_old read from hin.
__global__ __launch_bounds__(256) void lstm_step_fb(
    const __bf16* __restrict__ Z, const __bf16* __restrict__ WhT,
    const __bf16* __restrict__ hin, __bf16* __restrict__ hout,
    float* __restrict__ cst, __bf16* __restrict__ Hout,
    const int* __restrict__ plen, int t) {
    __shared__ float zl[64 * 65];
    const int w = blockIdx.x, tid = threadIdx.x;
    const int wv = tid >> 6, l = tid & 63;
    const int lr = l & 15, lh = l >> 4;

    f32x4 acc[4];
    #pragma unroll
    for (int mt = 0; mt < 4; ++mt) acc[mt] = (f32x4){0.f, 0.f, 0.f, 0.f};
    const __bf16* Bp = WhT + (size_t)(w * 64 + wv * 16 + lr) * H_ + lh * 8;
    const __bf16* Ap = hin + (size_t)lr * H_ + lh * 8;
    for (int kk = 0; kk < 20; ++kk) {
        bf16x8 bfv = *reinterpret_cast<const bf16x8*>(Bp + kk * 32);
        #pragma unroll
        for (int mt = 0; mt < 4; ++mt) {
            bf16x8 af = *reinterpret_cast<const bf16x8*>(Ap + (size_t)mt * 16 * H_ + kk * 32);
            acc[mt] = __builtin_amdgcn_mfma_f32_16x16x32_bf16(af, bfv, acc[mt], 0, 0, 0);
        }
    }
    {
        int cl = wv * 16 + lr;
        #pragma unroll
        for (int mt = 0; mt < 4; ++mt)
            #pragma unroll
            for (int r = 0; r < 4; ++r)
                zl[(mt * 16 + lh * 4 + r) * 65 + cl] = acc[mt][r];
    }
    __syncthreads();

    const int bb0 = tid >> 3, jp = tid & 7;
    #pragma unroll
    for (int it = 0; it < 2; ++it) {
        const int bb = (it ? bb0 + 32 : bb0);
        const int pl = plen[bb];
        const bf16x8 zq = *reinterpret_cast<const bf16x8*>(
            Z + ((size_t)t * B_ + bb) * G4H + w * 64 + 8 * jp);
        const float* zp = &zl[bb * 65 + 8 * jp];
        const size_t co = (size_t)w * 16 + 2 * jp;
        union { __bf16 h[2]; unsigned u; } ho_, hi_;
        hi_.u = *reinterpret_cast<const unsigned*>(hin + (size_t)bb * H_ + co);
        #pragma unroll
        for (int e = 0; e < 2; ++e) {
            size_t sidx = (size_t)bb * H_ + co + e;
            float zi = zp[4 * e + 0] + (float)zq[4 * e + 0];
            float zf = zp[4 * e + 1] + (float)zq[4 * e + 1];
            float zg = zp[4 * e + 2] + (float)zq[4 * e + 2];
            float zo = zp[4 * e + 3] + (float)zq[4 * e + 3];
            float ig = sigm(zi), fg = sigm(zf), og = sigm(zo);
            float gg = tanhfast(zg);
            float cold = cst[sidx];
            float cnew = fg * cold + ig * gg;
            float hnew = og * tanhfast(cnew);
            bool m = t < pl;
            cst[sidx] = m ? cnew : cold;
            ho_.h[e] = m ? (__bf16)hnew : hi_.h[e];
        }
        *reinterpret_cast<unsigned*>(hout + (size_t)bb * H_ + co) = ho_.u;
        *reinterpret_cast<unsigned*>(Hout + ((size_t)bb * U_ + t) * H_ + co) = ho_.u;
    }
}

// ---------------------------------------------------------------------------
__global__ __launch_bounds__(256) void ln_kernel(
    __bf16* __restrict__ X, const float* __restrict__ gamma, const float* __restrict__ beta) {
    __shared__ float s1[256];
    __shared__ float s2[256];
    const int tid = threadIdx.x;
    __bf16* xp = X + (size_t)blockIdx.x * H_;
    float xv[3] = {0.f, 0.f, 0.f};
    float a = 0.f, b = 0.f;
    #pragma unroll
    for (int i = 0; i < 3; ++i) {
        int j = tid + 256 * i;
        if (j < H_) { float v = (float)xp[j]; xv[i] = v; a += v; b += v * v; }
    }
    s1[tid] = a; s2[tid] = b;
    __syncthreads();
    for (int st = 128; st > 0; st >>= 1) {
        if (tid < st) { s1[tid] += s1[tid + st]; s2[tid] += s2[tid + st]; }
        __syncthreads();
    }
    float mean = s1[0] * (1.f / H_);
    float var  = s2[0] * (1.f / H_) - mean * mean;
    float inv  = rsqrtf(var + 0.001f);
    #pragma unroll
    for (int i = 0; i < 3; ++i) {
        int j = tid + 256 * i;
        if (j < H_) xp[j] = (__bf16)((xv[i] - mean) * inv * gamma[j] + beta[j]);
    }
}

// ---------------------------------------------------------------------------
extern "C" void kernel_launch(void* const* d_in, const int* in_sizes, int n_in,
                              void* d_out, int out_size, void* d_ws, size_t ws_size,
                              hipStream_t stream) {
    (void)in_sizes; (void)n_in; (void)out_size;
    const int*   tokens = (const int*)d_in[0];
    const int*   plen   = (const int*)d_in[1];
    const float* embed  = (const float*)d_in[2];
    const float* W0x = (const float*)d_in[3];
    const float* W0h = (const float*)d_in[4];
    const float* b0  = (const float*)d_in[5];
    const float* g0  = (const float*)d_in[6];
    const float* be0 = (const float*)d_in[7];
    const float* P0w = (const float*)d_in[8];
    const float* P0b = (const float*)d_in[9];
    const float* W1x = (const float*)d_in[10];
    const float* W1h = (const float*)d_in[11];
    const float* b1  = (const float*)d_in[12];
    const float* g1  = (const float*)d_in[13];
    const float* be1 = (const float*)d_in[14];
    const float* P1w = (const float*)d_in[15];
    const float* P1b = (const float*)d_in[16];
    float* out = (float*)d_out;

    char* p = (char*)d_ws;
    size_t used = 0;
    auto take = [&](size_t bytes) {
        char* r = p; size_t pad = (bytes + 255) & ~(size_t)255;
        p += pad; used += pad; return r;
    };
    __bf16* WT0x_ = (__bf16*)take((size_t)G4H * D_ * 2);
    __bf16* WT0h_ = (__bf16*)take((size_t)G4H * H_ * 2);
    __bf16* WT1x_ = (__bf16*)take((size_t)G4H * P_ * 2);
    __bf16* WT1h_ = (__bf16*)take((size_t)G4H * H_ * 2);
    __bf16* PT0w_ = (__bf16*)take((size_t)P_ * H_ * 2);
    __bf16* PT1w_ = (__bf16*)take((size_t)P_ * H_ * 2);
    float*  b0r   = (float*)take(G4H * 4);
    float*  b1r   = (float*)take(G4H * 4);
    __bf16* hb0   = (__bf16*)take((size_t)B_ * H_ * 2);
    __bf16* hb1   = (__bf16*)take((size_t)B_ * H_ * 2);
    float*  cst   = (float*)take((size_t)B_ * H_ * 4);
    unsigned* bar = (unsigned*)take(512);
    __bf16* Hbuf  = (__bf16*)take((size_t)B_ * U_ * H_ * 2);
    __bf16* Z     = (__bf16*)take((size_t)B_ * U_ * G4H * 2);  // [U][B][4H]

    if (used > ws_size) {
        fprintf(stderr, "kernel_launch: ws_size too small (%zu < %zu)\n",
                ws_size, used);
        return;
    }
    // Xbf aliases d_out (67 MB f32): dead before the final GEMM overwrites d_out.
    __bf16* Xbf = (__bf16*)d_out;

    dim3 blk(256);
    wconv_kernel<<<(D_ * G4H + 255) / 256, blk, 0, stream>>>(W0x, WT0x_, D_, G4H, 1);
    wconv_kernel<<<(H_ * G4H + 255) / 256, blk, 0, stream>>>(W0h, WT0h_, H_, G4H, 1);
    wconv_kernel<<<(P_ * G4H + 255) / 256, blk, 0, stream>>>(W1x, WT1x_, P_, G4H, 1);
    wconv_kernel<<<(H_ * G4H + 255) / 256, blk, 0, stream>>>(W1h, WT1h_, H_, G4H, 1);
    wconv_kernel<<<(H_ * P_ + 255) / 256, blk, 0, stream>>>(P0w, PT0w_, H_, P_, 0);
    wconv_kernel<<<(H_ * P_ + 255) / 256, blk, 0, stream>>>(P1w, PT1w_, H_, P_, 0);
    breorder_kernel<<<10, blk, 0, stream>>>(b0, b0r);
    breorder_kernel<<<10, blk, 0, stream>>>(b1, b1r);
    gather_kernel<<<(B_ * U_ * D_ / 4 + 255) / 256, blk, 0, stream>>>(tokens, embed, Xbf);

    // Recurrent layer driver: cooperative persistent kernel; on launch error,
    // print diagnostics and fall back to 512 per-step launches.
    auto run_lstm = [&](const __bf16* Zc, const __bf16* Wc) {
        zstate_kernel<<<(B_ * H_ + 255) / 256, blk, 0, stream>>>(hb0, hb1, cst, bar);
        __bf16* h0a = hb0; __bf16* h1a = hb1; __bf16* Ha = Hbuf;
        const int* pl = plen; unsigned* ba = bar;
        void* args[] = { (void*)&Zc, (void*)&Wc, (void*)&h0a, (void*)&h1a,
                         (void*)&Ha, (void*)&pl, (void*)&ba };
        hipError_t ce = hipLaunchCooperativeKernel((void*)lstm_seq_kernel,
                                                   dim3(NWG), dim3(256), args, 0, stream);
        if (ce != hipSuccess) {
            fprintf(stderr, "[lstm] coop launch failed: %d (%s) — per-step fallback\n",
                    (int)ce, hipGetErrorName(ce));
            for (int t = 0; t < U_; ++t) {
                const __bf16* hi = (t & 1) ? hb1 : hb0;
                __bf16*       ho = (t & 1) ? hb0 : hb1;
                lstm_step_fb<<<NWG, blk, 0, stream>>>(Zc, Wc, hi, ho, cst, Hbuf, plen, t);
            }
        }
    };

    // ---- layer 0 ----
    gemm_kernel<<<dim3(G4H / 64, B_ * U_ / 64), blk, 0, stream>>>(
        Xbf, WT0x_, b0r, nullptr, Z, B_ * U_, G4H, D_, 1);
    run_lstm(Z, WT0h_);
    ln_kernel<<<B_ * U_, blk, 0, stream>>>(Hbuf, g0, be0);
    gemm_kernel<<<dim3(P_ / 64, B_ * U_ / 64), blk, 0, stream>>>(
        Hbuf, PT0w_, P0b, nullptr, Xbf, B_ * U_, P_, H_, 0);

    // ---- layer 1 ----
    gemm_kernel<<<dim3(G4H / 64, B_ * U_ / 64), blk, 0, stream>>>(
        Xbf, WT1x_, b1r, nullptr, Z, B_ * U_, G4H, P_, 1);
    run_lstm(Z, WT1h_);
    ln_kernel<<<B_ * U_, blk, 0, stream>>>(Hbuf, g1, be1);
    gemm_kernel<<<dim3(P_ / 64, B_ * U_ / 64), blk, 0, stream>>>(
        Hbuf, PT1w_, P1b, out, nullptr, B_ * U_, P_, H_, 0);
}